// Round 3
// baseline (339.413 us; speedup 1.0000x reference)
//
#include <hip/hip_runtime.h>
#include <hip/hip_bf16.h>

#define N 1024
#define DIM 64
#define MDIM 16
#define EH 258    // edge mlp hidden
#define CH 64     // coors mlp hidden
#define HH 128    // hidden mlp hidden

// Precompute A[i][k] = feats[i] @ eW1[0:64, k] + eb1[k]        (1024 x 258)
//            BT[k][i] = feats[i] @ eW1[64:128, k]              (258 x 1024, transposed)
__global__ __launch_bounds__(256) void eg_pre(
    const float* __restrict__ feats, const float* __restrict__ eW1,
    const float* __restrict__ eb1,
    float* __restrict__ A, float* __restrict__ BT)
{
  __shared__ float f[DIM];
  int i = blockIdx.x, t = threadIdx.x;
  if (t < DIM) f[t] = feats[i * DIM + t];
  __syncthreads();
  for (int k = t; k < EH; k += 256) {
    float a = 0.f, b2 = 0.f;
#pragma unroll 8
    for (int d = 0; d < DIM; ++d) {
      float fd = f[d];
      a  = fmaf(fd, eW1[d * EH + k], a);
      b2 = fmaf(fd, eW1[(DIM + d) * EH + k], b2);
    }
    A[i * EH + k]  = a + eb1[k];
    BT[k * N + i]  = b2;
  }
}

__global__ __launch_bounds__(256) void eg_main(
    const float* __restrict__ feats, const float* __restrict__ coors,
    const float* __restrict__ eW1, const float* __restrict__ eW2,
    const float* __restrict__ eb2, const float* __restrict__ cW1,
    const float* __restrict__ cb1, const float* __restrict__ cW2,
    const float* __restrict__ cb2, const float* __restrict__ hW1,
    const float* __restrict__ hb1, const float* __restrict__ hW2,
    const float* __restrict__ hb2,
    const float* __restrict__ A, const float* __restrict__ BT,
    float* __restrict__ out)
{
  __shared__ float sA[EH], sW3[EH];
  __shared__ float sEW2[EH * MDIM];   // 258x16
  __shared__ float sCW1[MDIM * CH];   // 16x64
  __shared__ float sCB1[CH], sCW2[CH];
  __shared__ float sEB2[MDIM];
  __shared__ float sRed[4][20];
  __shared__ float sMi[MDIM];
  __shared__ float sFeat[DIM];
  __shared__ float sHid[HH];

  int i = blockIdx.x, t = threadIdx.x;

  for (int k = t; k < EH; k += 256) { sA[k] = A[i * EH + k]; sW3[k] = eW1[128 * EH + k]; }
  for (int k = t; k < EH * MDIM; k += 256) sEW2[k] = eW2[k];
  for (int k = t; k < MDIM * CH; k += 256) sCW1[k] = cW1[k];
  if (t < CH)   { sCB1[t] = cb1[t]; sCW2[t] = cW2[t]; }
  if (t < MDIM) sEB2[t] = eb2[t];
  if (t < DIM)  sFeat[t] = feats[i * DIM + t];
  __syncthreads();

  float cx = coors[i * 3], cy = coors[i * 3 + 1], cz = coors[i * 3 + 2];
  float cb2v = cb2[0];

  float macc[MDIM];
#pragma unroll
  for (int c = 0; c < MDIM; ++c) macc[c] = 0.f;
  float cax = 0.f, cay = 0.f, caz = 0.f;

  for (int jt = 0; jt < N; jt += 256) {
    int j = jt + t;
    float rx = cx - coors[j * 3], ry = cy - coors[j * 3 + 1], rz = cz - coors[j * 3 + 2];
    float dist = sqrtf(fmaf(rx, rx, fmaf(ry, ry, rz * rz)));

    float m[MDIM];
#pragma unroll
    for (int c = 0; c < MDIM; ++c) m[c] = sEB2[c];

    for (int k = 0; k < EH; ++k) {
      float h = fmaf(dist, sW3[k], sA[k] + BT[k * N + j]);
      h = fmaxf(h, 0.f);
#pragma unroll
      for (int c = 0; c < MDIM; ++c) m[c] = fmaf(h, sEW2[k * MDIM + c], m[c]);
    }

    // coors mlp: 16 -> 64 -> 1
    float w = cb2v;
#pragma unroll 4
    for (int c2 = 0; c2 < CH; ++c2) {
      float acc = sCB1[c2];
#pragma unroll
      for (int c = 0; c < MDIM; ++c) acc = fmaf(m[c], sCW1[c * CH + c2], acc);
      w = fmaf(fmaxf(acc, 0.f), sCW2[c2], w);
    }

    cax = fmaf(w, rx, cax); cay = fmaf(w, ry, cay); caz = fmaf(w, rz, caz);
#pragma unroll
    for (int c = 0; c < MDIM; ++c) macc[c] += m[c];
  }

  // block-wide reduction of 19 values (m_i[16], coors_acc[3])
  int lane = t & 63, wv = t >> 6;
#pragma unroll
  for (int off = 32; off > 0; off >>= 1) {
#pragma unroll
    for (int c = 0; c < MDIM; ++c) macc[c] += __shfl_down(macc[c], off, 64);
    cax += __shfl_down(cax, off, 64);
    cay += __shfl_down(cay, off, 64);
    caz += __shfl_down(caz, off, 64);
  }
  if (lane == 0) {
#pragma unroll
    for (int c = 0; c < MDIM; ++c) sRed[wv][c] = macc[c];
    sRed[wv][16] = cax; sRed[wv][17] = cay; sRed[wv][18] = caz;
  }
  __syncthreads();
  if (t < 19) {
    float v = sRed[0][t] + sRed[1][t] + sRed[2][t] + sRed[3][t];
    if (t < MDIM) sMi[t] = v;
    else out[N * DIM + i * 3 + (t - MDIM)] = v;
  }
  __syncthreads();

  // hidden mlp: [feats(64), m_i(16)] -> 128 -> relu -> 64
  if (t < HH) {
    float acc = hb1[t];
#pragma unroll 8
    for (int d = 0; d < DIM; ++d) acc = fmaf(sFeat[d], hW1[d * HH + t], acc);
#pragma unroll
    for (int d = 0; d < MDIM; ++d) acc = fmaf(sMi[d], hW1[(DIM + d) * HH + t], acc);
    sHid[t] = fmaxf(acc, 0.f);
  }
  __syncthreads();
  if (t < DIM) {
    float acc = hb2[t];
#pragma unroll 8
    for (int c = 0; c < HH; ++c) acc = fmaf(sHid[c], hW2[c * DIM + t], acc);
    out[i * DIM + t] = acc;
  }
}

extern "C" void kernel_launch(void* const* d_in, const int* in_sizes, int n_in,
                              void* d_out, int out_size, void* d_ws, size_t ws_size,
                              hipStream_t stream) {
  const float* feats = (const float*)d_in[0];
  const float* coors = (const float*)d_in[1];
  const float* eW1   = (const float*)d_in[2];
  const float* eb1   = (const float*)d_in[3];
  const float* eW2   = (const float*)d_in[4];
  const float* eb2   = (const float*)d_in[5];
  const float* cW1   = (const float*)d_in[6];
  const float* cb1   = (const float*)d_in[7];
  const float* cW2   = (const float*)d_in[8];
  const float* cb2   = (const float*)d_in[9];
  const float* hW1   = (const float*)d_in[10];
  const float* hb1   = (const float*)d_in[11];
  const float* hW2   = (const float*)d_in[12];
  const float* hb2   = (const float*)d_in[13];

  float* A  = (float*)d_ws;          // 1024*258 floats
  float* BT = A + N * EH;            // 258*1024 floats
  float* out = (float*)d_out;

  eg_pre<<<N, 256, 0, stream>>>(feats, eW1, eb1, A, BT);
  eg_main<<<N, 256, 0, stream>>>(feats, coors, eW1, eW2, eb2, cW1, cb1, cW2, cb2,
                                 hW1, hb1, hW2, hb2, A, BT, out);
}

// Round 4
// 251.751 us; speedup vs baseline: 1.3482x; 1.3482x over previous
//
#include <hip/hip_runtime.h>
#include <hip/hip_bf16.h>

#define N 1024
#define DIM 64
#define MDIM 16
#define EH 258    // edge mlp hidden
#define CH 64     // coors mlp hidden
#define HH 128    // hidden mlp hidden
#define PRE_ROWS 8

// Precompute A[i][k] = feats[i] @ eW1[0:64, k] + eb1[k]        (1024 x 258)
//            BT[k][i] = feats[i] @ eW1[64:128, k]              (258 x 1024, transposed)
// 128 blocks x 8 rows each: eW1 global traffic = 128 * 133KB = 17MB (L2/L3-hit),
// 16 FMAs per eW1 element loaded.
__global__ __launch_bounds__(256) void eg_pre(
    const float* __restrict__ feats, const float* __restrict__ eW1,
    const float* __restrict__ eb1,
    float* __restrict__ A, float* __restrict__ BT)
{
  __shared__ float sf[PRE_ROWS][DIM];
  int ib = blockIdx.x, t = threadIdx.x;
  for (int q = t; q < PRE_ROWS * DIM; q += 256)
    sf[q >> 6][q & 63] = feats[ib * PRE_ROWS * DIM + q];
  __syncthreads();
  for (int k = t; k < EH; k += 256) {
    float bias = eb1[k];
    float a[PRE_ROWS], bv[PRE_ROWS];
#pragma unroll
    for (int ii = 0; ii < PRE_ROWS; ++ii) { a[ii] = bias; bv[ii] = 0.f; }
#pragma unroll 4
    for (int d = 0; d < DIM; ++d) {
      float wt = eW1[d * EH + k];
      float wb = eW1[(DIM + d) * EH + k];
#pragma unroll
      for (int ii = 0; ii < PRE_ROWS; ++ii) {
        a[ii]  = fmaf(sf[ii][d], wt, a[ii]);
        bv[ii] = fmaf(sf[ii][d], wb, bv[ii]);
      }
    }
#pragma unroll
    for (int ii = 0; ii < PRE_ROWS; ++ii) {
      A[(ib * PRE_ROWS + ii) * EH + k] = a[ii];
      BT[k * N + ib * PRE_ROWS + ii]   = bv[ii];
    }
  }
}

// One block per row i; 256 threads; each thread owns 4 consecutive j (j0=4t..4t+3).
__global__ __launch_bounds__(256) void eg_main(
    const float* __restrict__ feats, const float* __restrict__ coors,
    const float* __restrict__ eW1, const float* __restrict__ eW2,
    const float* __restrict__ eb2, const float* __restrict__ cW1,
    const float* __restrict__ cb1, const float* __restrict__ cW2,
    const float* __restrict__ cb2, const float* __restrict__ hW1,
    const float* __restrict__ hb1, const float* __restrict__ hW2,
    const float* __restrict__ hb2,
    const float* __restrict__ A, const float* __restrict__ BT,
    float* __restrict__ out)
{
  __shared__ float2 sAW[EH];          // {A[i][k], eW1[128][k]}
  __shared__ float4 sEW2[EH][4];      // 258 x 16
  __shared__ float sCW1[MDIM * CH];   // 16x64
  __shared__ float sCB1[CH], sCW2[CH];
  __shared__ float sEB2[MDIM];
  __shared__ float sRed[4][20];
  __shared__ float sMi[MDIM];
  __shared__ float sFeat[DIM];
  __shared__ float sHid[HH];

  int i = blockIdx.x, t = threadIdx.x;

  for (int k = t; k < EH; k += 256)
    sAW[k] = make_float2(A[i * EH + k], eW1[128 * EH + k]);
  {
    const float4* e4 = (const float4*)eW2;
    for (int q = t; q < EH * 4; q += 256) sEW2[q >> 2][q & 3] = e4[q];
  }
  for (int k = t; k < MDIM * CH; k += 256) sCW1[k] = cW1[k];
  if (t < CH)   { sCB1[t] = cb1[t]; sCW2[t] = cW2[t]; }
  if (t < MDIM) sEB2[t] = eb2[t];
  if (t < DIM)  sFeat[t] = feats[i * DIM + t];
  __syncthreads();

  float cx = coors[i * 3], cy = coors[i * 3 + 1], cz = coors[i * 3 + 2];
  float cb2v = cb2[0];

  // 4 consecutive j's: coords via 3 float4 loads
  float jx[4], jy[4], jz[4];
  {
    const float4* c4 = (const float4*)coors;
    float4 ca = c4[t * 3 + 0], cb = c4[t * 3 + 1], cc = c4[t * 3 + 2];
    jx[0] = ca.x; jy[0] = ca.y; jz[0] = ca.z;
    jx[1] = ca.w; jy[1] = cb.x; jz[1] = cb.y;
    jx[2] = cb.z; jy[2] = cb.w; jz[2] = cc.x;
    jx[3] = cc.y; jy[3] = cc.z; jz[3] = cc.w;
  }
  float rx[4], ry[4], rz[4], dist[4];
#pragma unroll
  for (int jj = 0; jj < 4; ++jj) {
    rx[jj] = cx - jx[jj]; ry[jj] = cy - jy[jj]; rz[jj] = cz - jz[jj];
    dist[jj] = sqrtf(fmaf(rx[jj], rx[jj], fmaf(ry[jj], ry[jj], rz[jj] * rz[jj])));
  }

  float m[4][MDIM];
#pragma unroll
  for (int jj = 0; jj < 4; ++jj)
#pragma unroll
    for (int c = 0; c < MDIM; ++c) m[jj][c] = sEB2[c];

  const float4* BT4 = (const float4*)BT;
#pragma unroll 2
  for (int k = 0; k < EH; ++k) {
    float2 aw = sAW[k];
    float4 bv = BT4[k * (N / 4) + t];
    float bb[4] = {bv.x, bv.y, bv.z, bv.w};
    float4 e0 = sEW2[k][0], e1 = sEW2[k][1], e2 = sEW2[k][2], e3 = sEW2[k][3];
    float ew[16] = {e0.x, e0.y, e0.z, e0.w, e1.x, e1.y, e1.z, e1.w,
                    e2.x, e2.y, e2.z, e2.w, e3.x, e3.y, e3.z, e3.w};
#pragma unroll
    for (int jj = 0; jj < 4; ++jj) {
      float h = fmaxf(fmaf(dist[jj], aw.y, aw.x + bb[jj]), 0.f);
#pragma unroll
      for (int c = 0; c < MDIM; ++c) m[jj][c] = fmaf(h, ew[c], m[jj][c]);
    }
  }

  float macc[MDIM];
#pragma unroll
  for (int c = 0; c < MDIM; ++c) macc[c] = 0.f;
  float cax = 0.f, cay = 0.f, caz = 0.f;

#pragma unroll
  for (int jj = 0; jj < 4; ++jj) {
    // coors mlp: 16 -> 64 -> 1
    float w = cb2v;
#pragma unroll 4
    for (int c2 = 0; c2 < CH; ++c2) {
      float acc = sCB1[c2];
#pragma unroll
      for (int c = 0; c < MDIM; ++c) acc = fmaf(m[jj][c], sCW1[c * CH + c2], acc);
      w = fmaf(fmaxf(acc, 0.f), sCW2[c2], w);
    }
    cax = fmaf(w, rx[jj], cax); cay = fmaf(w, ry[jj], cay); caz = fmaf(w, rz[jj], caz);
#pragma unroll
    for (int c = 0; c < MDIM; ++c) macc[c] += m[jj][c];
  }

  // block-wide reduction of 19 values (m_i[16], coors_acc[3])
  int lane = t & 63, wv = t >> 6;
#pragma unroll
  for (int off = 32; off > 0; off >>= 1) {
#pragma unroll
    for (int c = 0; c < MDIM; ++c) macc[c] += __shfl_down(macc[c], off, 64);
    cax += __shfl_down(cax, off, 64);
    cay += __shfl_down(cay, off, 64);
    caz += __shfl_down(caz, off, 64);
  }
  if (lane == 0) {
#pragma unroll
    for (int c = 0; c < MDIM; ++c) sRed[wv][c] = macc[c];
    sRed[wv][16] = cax; sRed[wv][17] = cay; sRed[wv][18] = caz;
  }
  __syncthreads();
  if (t < 19) {
    float v = sRed[0][t] + sRed[1][t] + sRed[2][t] + sRed[3][t];
    if (t < MDIM) sMi[t] = v;
    else out[N * DIM + i * 3 + (t - MDIM)] = v;
  }
  __syncthreads();

  // hidden mlp: [feats(64), m_i(16)] -> 128 -> relu -> 64
  if (t < HH) {
    float acc = hb1[t];
#pragma unroll 8
    for (int d = 0; d < DIM; ++d) acc = fmaf(sFeat[d], hW1[d * HH + t], acc);
#pragma unroll
    for (int d = 0; d < MDIM; ++d) acc = fmaf(sMi[d], hW1[(DIM + d) * HH + t], acc);
    sHid[t] = fmaxf(acc, 0.f);
  }
  __syncthreads();
  if (t < DIM) {
    float acc = hb2[t];
#pragma unroll 8
    for (int c = 0; c < HH; ++c) acc = fmaf(sHid[c], hW2[c * DIM + t], acc);
    out[i * DIM + t] = acc;
  }
}

extern "C" void kernel_launch(void* const* d_in, const int* in_sizes, int n_in,
                              void* d_out, int out_size, void* d_ws, size_t ws_size,
                              hipStream_t stream) {
  const float* feats = (const float*)d_in[0];
  const float* coors = (const float*)d_in[1];
  const float* eW1   = (const float*)d_in[2];
  const float* eb1   = (const float*)d_in[3];
  const float* eW2   = (const float*)d_in[4];
  const float* eb2   = (const float*)d_in[5];
  const float* cW1   = (const float*)d_in[6];
  const float* cb1   = (const float*)d_in[7];
  const float* cW2   = (const float*)d_in[8];
  const float* cb2   = (const float*)d_in[9];
  const float* hW1   = (const float*)d_in[10];
  const float* hb1   = (const float*)d_in[11];
  const float* hW2   = (const float*)d_in[12];
  const float* hb2   = (const float*)d_in[13];

  float* A  = (float*)d_ws;          // 1024*258 floats
  float* BT = A + N * EH;            // 258*1024 floats
  float* out = (float*)d_out;

  eg_pre<<<N / PRE_ROWS, 256, 0, stream>>>(feats, eW1, eb1, A, BT);
  eg_main<<<N, 256, 0, stream>>>(feats, coors, eW1, eW2, eb2, cW1, cb1, cW2, cb2,
                                 hW1, hb1, hW2, hb2, A, BT, out);
}

// Round 5
// 160.582 us; speedup vs baseline: 2.1136x; 1.5677x over previous
//
#include <hip/hip_runtime.h>
#include <hip/hip_bf16.h>
#include <stdint.h>

#define N 1024
#define DIM 64
#define MDIM 16
#define EH 258    // edge mlp hidden
#define EHP 264   // padded Bb row stride (elements); 528 bytes, 16B-aligned
#define CH 64
#define HH 128
#define PRE_ROWS 8

typedef __bf16 bf16x8 __attribute__((ext_vector_type(8)));
typedef float f32x4 __attribute__((ext_vector_type(4)));
typedef uint32_t u32x4 __attribute__((ext_vector_type(4)));
union B8 { uint32_t u[4]; bf16x8 v; };

__device__ __forceinline__ uint32_t cvtpk(float lo, float hi) {
  uint32_t r;
  asm("v_cvt_pk_bf16_f32 %0, %1, %2" : "=v"(r) : "v"(lo), "v"(hi));
  return r;
}
__device__ __forceinline__ float bflo(uint32_t u) { return __uint_as_float(u << 16); }
__device__ __forceinline__ float bfhi(uint32_t u) { return __uint_as_float(u & 0xffff0000u); }

// A[i][k] = feats[i] @ eW1[0:64,k] + eb1[k]   (f32, stride EH)
// Bb[j][k] = feats[j] @ eW1[64:128,k]         (bf16, row-major, stride EHP)
__global__ __launch_bounds__(256) void eg_pre(
    const float* __restrict__ feats, const float* __restrict__ eW1,
    const float* __restrict__ eb1,
    float* __restrict__ A, __hip_bfloat16* __restrict__ Bb)
{
  __shared__ float sf[PRE_ROWS][DIM];
  int ib = blockIdx.x, t = threadIdx.x;
  for (int q = t; q < PRE_ROWS * DIM; q += 256)
    sf[q >> 6][q & 63] = feats[ib * PRE_ROWS * DIM + q];
  __syncthreads();
  for (int k = t; k < EH; k += 256) {
    float bias = eb1[k];
    float a[PRE_ROWS], bv[PRE_ROWS];
#pragma unroll
    for (int ii = 0; ii < PRE_ROWS; ++ii) { a[ii] = bias; bv[ii] = 0.f; }
#pragma unroll 4
    for (int d = 0; d < DIM; ++d) {
      float wt = eW1[d * EH + k];
      float wb = eW1[(DIM + d) * EH + k];
#pragma unroll
      for (int ii = 0; ii < PRE_ROWS; ++ii) {
        a[ii]  = fmaf(sf[ii][d], wt, a[ii]);
        bv[ii] = fmaf(sf[ii][d], wb, bv[ii]);
      }
    }
#pragma unroll
    for (int ii = 0; ii < PRE_ROWS; ++ii) {
      A[(ib * PRE_ROWS + ii) * EH + k] = a[ii];
      Bb[(ib * PRE_ROWS + ii) * EHP + k] = __float2bfloat16(bv[ii]);
    }
  }
}

__global__ __launch_bounds__(256, 2) void eg_main(
    const float* __restrict__ feats, const float* __restrict__ coors,
    const float* __restrict__ eW1, const float* __restrict__ eW2,
    const float* __restrict__ eb2, const float* __restrict__ cW1,
    const float* __restrict__ cb1, const float* __restrict__ cW2,
    const float* __restrict__ cb2, const float* __restrict__ hW1,
    const float* __restrict__ hb1, const float* __restrict__ hW2,
    const float* __restrict__ hb2,
    const float* __restrict__ A, const __hip_bfloat16* __restrict__ Bb,
    float* __restrict__ out)
{
  __shared__ float sEW2f[EH * MDIM];                 // 16.5 KB, f32 copy of eW2
  __shared__ __align__(16) float sA[EHP];
  __shared__ __align__(16) float sW3[EHP];
  __shared__ float sCB1[CH], sCW2[CH], sEB2[MDIM], sFeat[DIM];
  __shared__ float4 sRel4[N];                        // {rx,ry,rz,dist} per j (16 KB)
  __shared__ union {
    float cw1[MDIM * CH];                            // used only pre-main-loop
    struct { float redm[4][16]; float redc[4][3]; float mi[MDIM]; float hid[HH]; } e;
  } sU;

  const int i = blockIdx.x, t = threadIdx.x;
  const int lane = t & 63, wv = t >> 6;
  const int r16 = lane & 15, g = lane >> 4;

  // ---- cooperative staging ----
  for (int q = t; q < EH * MDIM; q += 256) sEW2f[q] = eW2[q];
  for (int q = t; q < EH; q += 256) { sA[q] = A[i * EH + q]; sW3[q] = eW1[128 * EH + q]; }
  for (int q = t; q < MDIM * CH; q += 256) sU.cw1[q] = cW1[q];
  if (t < CH)   { sCB1[t] = cb1[t]; sCW2[t] = cW2[t]; }
  if (t < MDIM) sEB2[t] = eb2[t];
  if (t < DIM)  sFeat[t] = feats[i * DIM + t];
  {
    float cx = coors[i * 3], cy = coors[i * 3 + 1], cz = coors[i * 3 + 2];
    const float4* c4 = (const float4*)coors;
    float4 ca = c4[t * 3 + 0], cb = c4[t * 3 + 1], cc = c4[t * 3 + 2];
    float jx[4] = {ca.x, ca.w, cb.z, cc.y};
    float jy[4] = {ca.y, cb.x, cb.w, cc.z};
    float jz[4] = {ca.z, cb.y, cc.x, cc.w};
#pragma unroll
    for (int q = 0; q < 4; ++q) {
      float rx = cx - jx[q], ry = cy - jy[q], rz = cz - jz[q];
      float d = sqrtf(fmaf(rx, rx, fmaf(ry, ry, rz * rz)));
      sRel4[t * 4 + q] = make_float4(rx, ry, rz, d);
    }
  }
  __syncthreads();

  // ---- per-lane resident fragments / constants ----
  f32x4 eb2r;
#pragma unroll
  for (int r = 0; r < 4; ++r) eb2r[r] = sEB2[4 * g + r];
  float tw0[4], tw1[4];
#pragma unroll
  for (int r = 0; r < 4; ++r) {
    tw0[r] = sEW2f[256 * MDIM + 4 * g + r];
    tw1[r] = sEW2f[257 * MDIM + 4 * g + r];
  }
  float a256 = sA[256], a257 = sA[257], w356 = sW3[256], w357 = sW3[257];
  float cb2v = cb2[0];
  // cW1^T A-fragments (K padded 16->32: groups g>=2 are zero)
  B8 fcw1[4];
#pragma unroll
  for (int T = 0; T < 4; ++T) {
    float cv[8];
#pragma unroll
    for (int e = 0; e < 8; ++e)
      cv[e] = (g < 2) ? sU.cw1[(8 * g + e) * CH + 16 * T + r16] : 0.f;
    fcw1[T].u[0] = cvtpk(cv[0], cv[1]); fcw1[T].u[1] = cvtpk(cv[2], cv[3]);
    fcw1[T].u[2] = cvtpk(cv[4], cv[5]); fcw1[T].u[3] = cvtpk(cv[6], cv[7]);
  }
  __syncthreads();   // all gathers from sU.cw1 done before epilogue overwrites sU

  const f32x4* sA4 = (const f32x4*)sA;
  const f32x4* sW34 = (const f32x4*)sW3;
  const char* Bbyte = (const char*)Bb;

  float macc[4] = {0.f, 0.f, 0.f, 0.f};
  float cax = 0.f, cay = 0.f, caz = 0.f;

  for (int p = 0; p < 2; ++p) {
    const int jb = wv * 16 + p * 512;     // + tt*64 + r16
    float djp[8];
    f32x4 D[8];
#pragma unroll
    for (int tt = 0; tt < 8; ++tt) {
      djp[tt] = sRel4[jb + tt * 64 + r16].w;
      D[tt] = eb2r;
    }

    for (int s = 0; s < 8; ++s) {
      const int kb = s * 32 + g * 8;
      // B tiles for this k-step (global bf16, L2-resident)
      u32x4 bq[8];
#pragma unroll
      for (int tt = 0; tt < 8; ++tt)
        bq[tt] = *(const u32x4*)(Bbyte + (size_t)((jb + tt * 64 + r16) * (EHP * 2) + kb * 2));
      // A / W3 octets (wave-uniform per group)
      f32x4 af0 = sA4[(kb >> 2)], af1 = sA4[(kb >> 2) + 1];
      f32x4 wf0 = sW34[(kb >> 2)], wf1 = sW34[(kb >> 2) + 1];
      // eW2^T A-fragment for this k-step
      float fe[8];
#pragma unroll
      for (int e = 0; e < 8; ++e) fe[e] = sEW2f[(kb + e) * MDIM + r16];
      B8 few;
      few.u[0] = cvtpk(fe[0], fe[1]); few.u[1] = cvtpk(fe[2], fe[3]);
      few.u[2] = cvtpk(fe[4], fe[5]); few.u[3] = cvtpk(fe[6], fe[7]);

#pragma unroll
      for (int tt = 0; tt < 8; ++tt) {
        float hh[8];
#pragma unroll
        for (int e = 0; e < 8; ++e) {
          uint32_t u = bq[tt][e >> 1];
          float b = (e & 1) ? bfhi(u) : bflo(u);
          float av = (e < 4) ? af0[e & 3] : af1[e & 3];
          float wv3 = (e < 4) ? wf0[e & 3] : wf1[e & 3];
          hh[e] = fmaxf(fmaf(djp[tt], wv3, av + b), 0.f);
        }
        B8 hb;
        hb.u[0] = cvtpk(hh[0], hh[1]); hb.u[1] = cvtpk(hh[2], hh[3]);
        hb.u[2] = cvtpk(hh[4], hh[5]); hb.u[3] = cvtpk(hh[6], hh[7]);
        D[tt] = __builtin_amdgcn_mfma_f32_16x16x32_bf16(few.v, hb.v, D[tt], 0, 0, 0);
      }
    }

    // ---- per-tile tail + coors MLP + accumulation ----
#pragma unroll
    for (int tt = 0; tt < 8; ++tt) {
      const int j = jb + tt * 64 + r16;
      float4 rl = sRel4[j];
      uint32_t bt = *(const uint32_t*)(Bbyte + (size_t)(j * (EHP * 2) + 512));
      float h6 = fmaxf(fmaf(rl.w, w356, a256 + bflo(bt)), 0.f);
      float h7 = fmaxf(fmaf(rl.w, w357, a257 + bfhi(bt)), 0.f);
#pragma unroll
      for (int r = 0; r < 4; ++r) {
        D[tt][r] = fmaf(h6, tw0[r], D[tt][r]);
        D[tt][r] = fmaf(h7, tw1[r], D[tt][r]);
        macc[r] += D[tt][r];
      }
      // redistribute m^T D-frag -> B-frag (K padded to 32, zeros for k>=16)
      uint32_t p0 = cvtpk(D[tt][0], D[tt][1]);
      uint32_t p1 = cvtpk(D[tt][2], D[tt][3]);
      int s0 = r16 + (((2 * g) & 3) << 4);
      int s1 = r16 + (((2 * g + 1) & 3) << 4);
      uint32_t b0 = (uint32_t)__shfl((int)p0, s0, 64);
      uint32_t b1 = (uint32_t)__shfl((int)p1, s0, 64);
      uint32_t b2 = (uint32_t)__shfl((int)p0, s1, 64);
      uint32_t b3 = (uint32_t)__shfl((int)p1, s1, 64);
      B8 mf;
      mf.u[0] = (g < 2) ? b0 : 0u; mf.u[1] = (g < 2) ? b1 : 0u;
      mf.u[2] = (g < 2) ? b2 : 0u; mf.u[3] = (g < 2) ? b3 : 0u;
      float wacc = 0.f;
#pragma unroll
      for (int T = 0; T < 4; ++T) {
        f32x4 cbv;
#pragma unroll
        for (int r = 0; r < 4; ++r) cbv[r] = sCB1[16 * T + 4 * g + r];
        f32x4 hd = __builtin_amdgcn_mfma_f32_16x16x32_bf16(fcw1[T].v, mf.v, cbv, 0, 0, 0);
#pragma unroll
        for (int r = 0; r < 4; ++r)
          wacc = fmaf(fmaxf(hd[r], 0.f), sCW2[16 * T + 4 * g + r], wacc);
      }
      wacc += __shfl_xor(wacc, 16, 64);
      wacc += __shfl_xor(wacc, 32, 64);
      float w = cb2v + wacc;
      cax = fmaf(w, rl.x, cax); cay = fmaf(w, rl.y, cay); caz = fmaf(w, rl.z, caz);
    }
  }

  // ---- reductions: sum over r16 (j within wave) ----
#pragma unroll
  for (int off = 1; off < 16; off <<= 1) {
#pragma unroll
    for (int r = 0; r < 4; ++r) macc[r] += __shfl_xor(macc[r], off, 64);
    cax += __shfl_xor(cax, off, 64);
    cay += __shfl_xor(cay, off, 64);
    caz += __shfl_xor(caz, off, 64);
  }
  if (r16 == 0) {
#pragma unroll
    for (int r = 0; r < 4; ++r) sU.e.redm[wv][4 * g + r] = macc[r];
    if (g == 0) { sU.e.redc[wv][0] = cax; sU.e.redc[wv][1] = cay; sU.e.redc[wv][2] = caz; }
  }
  __syncthreads();
  if (t < MDIM)
    sU.e.mi[t] = sU.e.redm[0][t] + sU.e.redm[1][t] + sU.e.redm[2][t] + sU.e.redm[3][t];
  if (t >= 16 && t < 19) {
    int c = t - 16;
    out[N * DIM + i * 3 + c] =
        sU.e.redc[0][c] + sU.e.redc[1][c] + sU.e.redc[2][c] + sU.e.redc[3][c];
  }
  __syncthreads();

  // ---- hidden mlp: [feats(64), m_i(16)] -> 128 -> relu -> 64 ----
  if (t < HH) {
    float acc = hb1[t];
#pragma unroll 8
    for (int d = 0; d < DIM; ++d) acc = fmaf(sFeat[d], hW1[d * HH + t], acc);
#pragma unroll
    for (int d = 0; d < MDIM; ++d) acc = fmaf(sU.e.mi[d], hW1[(DIM + d) * HH + t], acc);
    sU.e.hid[t] = fmaxf(acc, 0.f);
  }
  __syncthreads();
  if (t < DIM) {
    float acc = hb2[t];
#pragma unroll 8
    for (int c = 0; c < HH; ++c) acc = fmaf(sU.e.hid[c], hW2[c * DIM + t], acc);
    out[i * DIM + t] = acc;
  }
}

extern "C" void kernel_launch(void* const* d_in, const int* in_sizes, int n_in,
                              void* d_out, int out_size, void* d_ws, size_t ws_size,
                              hipStream_t stream) {
  const float* feats = (const float*)d_in[0];
  const float* coors = (const float*)d_in[1];
  const float* eW1   = (const float*)d_in[2];
  const float* eb1   = (const float*)d_in[3];
  const float* eW2   = (const float*)d_in[4];
  const float* eb2   = (const float*)d_in[5];
  const float* cW1   = (const float*)d_in[6];
  const float* cb1   = (const float*)d_in[7];
  const float* cW2   = (const float*)d_in[8];
  const float* cb2   = (const float*)d_in[9];
  const float* hW1   = (const float*)d_in[10];
  const float* hb1   = (const float*)d_in[11];
  const float* hW2   = (const float*)d_in[12];
  const float* hb2   = (const float*)d_in[13];

  float* A = (float*)d_ws;                                     // 1024*258 f32
  __hip_bfloat16* Bb = (__hip_bfloat16*)((char*)d_ws + (size_t)N * EH * 4);  // 1024*264 bf16
  float* out = (float*)d_out;

  eg_pre<<<N / PRE_ROWS, 256, 0, stream>>>(feats, eW1, eb1, A, Bb);
  eg_main<<<N, 256, 0, stream>>>(feats, coors, eW1, eW2, eb2, cW1, cb1, cW2, cb2,
                                 hW1, hb1, hW2, hb2, A, Bb, out);
}